// Round 8
// baseline (321.706 us; speedup 1.0000x reference)
//
#include <hip/hip_runtime.h>
#include <hip/hip_fp16.h>

#define TPB 256
#define NBLK1 256          // CSR pass-1 blocks
#define BSH 10             // bucket shift: 1024 nodes per bucket (NB <= 128)
#define MAXBE 12288        // max edges/bucket -> 48KB LDS
#define KS 8               // head GEMM K-splits
#define GB 8               // head GEMM graphs per block
#define NPB 42             // gconv2 nodes/block (42*6 = 252 <= 256)
#define NPP 42             // gather_pool nodes/block (252 tasks -> 1/thread)
#define DBIN 64            // degree-sort bins

static inline int cdiv(long long a, int b){ return (int)((a + b - 1)/b); }

typedef _Float16 f16x8_t __attribute__((ext_vector_type(8)));
typedef float    f32x4_t __attribute__((ext_vector_type(4)));

// 8 halves = 16 bytes, 16-byte aligned -> single dwordx4 loads
struct __align__(16) h8 { __half2 a, b, c, d; };
struct float8 { float4 lo, hi; };
__device__ inline float8 h8tof8(h8 v){
    float2 t0 = __half22float2(v.a), t1 = __half22float2(v.b);
    float2 t2 = __half22float2(v.c), t3 = __half22float2(v.d);
    float8 r;
    r.lo = make_float4(t0.x, t0.y, t1.x, t1.y);
    r.hi = make_float4(t2.x, t2.y, t3.x, t3.y);
    return r;
}
__device__ inline h8 f8toh8(float8 v){
    h8 r;
    r.a = __floats2half2_rn(v.lo.x, v.lo.y); r.b = __floats2half2_rn(v.lo.z, v.lo.w);
    r.c = __floats2half2_rn(v.hi.x, v.hi.y); r.d = __floats2half2_rn(v.hi.z, v.hi.w);
    return r;
}
__device__ inline void f8acc(float8& a, float8 v){
    a.lo.x += v.lo.x; a.lo.y += v.lo.y; a.lo.z += v.lo.z; a.lo.w += v.lo.w;
    a.hi.x += v.hi.x; a.hi.y += v.hi.y; a.hi.z += v.hi.z; a.hi.w += v.hi.w;
}
__device__ inline void f8fma(float8& a, float8 v, float m){
    a.lo.x = fmaf(v.lo.x, m, a.lo.x); a.lo.y = fmaf(v.lo.y, m, a.lo.y);
    a.lo.z = fmaf(v.lo.z, m, a.lo.z); a.lo.w = fmaf(v.lo.w, m, a.lo.w);
    a.hi.x = fmaf(v.hi.x, m, a.hi.x); a.hi.y = fmaf(v.hi.y, m, a.hi.y);
    a.hi.z = fmaf(v.hi.z, m, a.hi.z); a.hi.w = fmaf(v.hi.w, m, a.hi.w);
}

// ---------- kernel 1: bucket count (blocks 0..NBLK1) + head split-K GEMM (rest) ----------
__global__ void k_bcnt_head(const int* __restrict__ dst, int* __restrict__ cnt_t,
                            int E, int NB, int chunk,
                            const float* __restrict__ feature, const float* __restrict__ Wf1,
                            float* __restrict__ partial, int G, int FEAT, int H){
    __shared__ int hist[128];
    __shared__ float sfeat[128*GB];
    int t = threadIdx.x;
    if(blockIdx.x < NBLK1){
        // ---- bucket count ----
        int blk = blockIdx.x;
        for(int i = t; i < NB; i += blockDim.x) hist[i] = 0;
        __syncthreads();
        int lo = blk*chunk, hi = min(E, lo + chunk);
        for(int e = lo + t; e < hi; e += blockDim.x)
            atomicAdd(&hist[dst[e] >> BSH], 1);
        __syncthreads();
        for(int b = t; b < NB; b += blockDim.x)
            cnt_t[blk*NB + b] = hist[b];
    } else {
        // ---- head split-K GEMM: partial[ks][g][h] ----
        int bid = (int)blockIdx.x - NBLK1;          // 0..1023
        int g0 = (bid & 127)*GB;
        int ks = bid >> 7;
        int Kc = (FEAT + KS - 1)/KS;
        int k0 = ks*Kc;
        int k1 = min(FEAT, k0 + Kc);
        int kc = k1 - k0;
        for(int idx = t; idx < GB*128; idx += 256){
            int gi = idx >> 7, kk = idx & 127;
            if(kk < kc) sfeat[kk*GB + gi] = feature[(size_t)(g0+gi)*FEAT + k0 + kk];
        }
        __syncthreads();
        int h  = t & 127;
        int gq = t >> 7;
        const float* wp = Wf1 + (size_t)k0*H + h;
        float4 a = {0.f,0.f,0.f,0.f};
        const float4* sf = (const float4*)(sfeat) + gq;
        for(int kk = 0; kk < kc; kk++){
            float w = wp[(size_t)kk*H];
            float4 f = sf[kk*2];
            a.x += f.x*w; a.y += f.y*w; a.z += f.z*w; a.w += f.w*w;
        }
        float* pp = partial + ((size_t)ks*G + g0 + gq*4)*H + h;
        pp[0] = a.x; pp[H] = a.y; pp[2*H] = a.z; pp[3*H] = a.w;
    }
}

// scatter with inline prefix: pairs[pos] = (local_dst<<17)|src  (needs N < 2^17)
// also zeroes pooled[G*48] (65536 threads >= 49152 elems; stream-ordered before use)
__global__ void k_bscatter(const int* __restrict__ ei, const int* __restrict__ cnt_t,
                           int* __restrict__ pairs, int E, int NB, int chunk,
                           float* __restrict__ pooled, int G){
    __shared__ int cur[128];
    __shared__ int st[128];
    int blk = blockIdx.x;
    int t = threadIdx.x;
    int zi = blk*256 + t;
    if(zi < G*48) pooled[zi] = 0.f;
    int myp = 0, myt = 0;
    for(int b2 = 0; b2 < NBLK1; b2++){
        int v = (t < NB) ? cnt_t[b2*NB + t] : 0;
        myp += (b2 < blk) ? v : 0;
        myt += v;
    }
    if(t < NB){ cur[t] = myp; st[t] = myt; }
    __syncthreads();
    if(t == 0){
        int run = 0;
        for(int b = 0; b < NB; b++){ int v = st[b]; st[b] = run; run += v; }
    }
    __syncthreads();
    if(t < NB) cur[t] += st[t];
    __syncthreads();
    int lo = blk*chunk, hi = min(E, lo + chunk);
    for(int e = lo + t; e < hi; e += blockDim.x){
        int s = ei[e], d = ei[E + e];
        int pos = atomicAdd(&cur[d >> BSH], 1);          // LDS atomic
        pairs[pos] = ((d & ((1 << BSH) - 1)) << 17) | s; // packed
    }
}

// R7: also emits per-bucket degree histogram dcnt[b][64] for the degree sort.
__global__ void k_build(const int* __restrict__ pairs, const int* __restrict__ cnt_t,
                        int* __restrict__ csr, int* __restrict__ cursor,
                        float* __restrict__ dinv, int* __restrict__ dcnt,
                        int N, int E, int NB){
    __shared__ int stot[128];
    __shared__ int sBase, sCnt;
    __shared__ int c[1024];
    __shared__ int so[1024];
    __shared__ int part[256];
    __shared__ int dhist[DBIN];
    __shared__ int csrl[MAXBE];
    int b = blockIdx.x;
    int t = threadIdx.x;
    if(t < DBIN) dhist[t] = 0;
    int myt = 0;
    for(int b2 = 0; b2 < NBLK1; b2++)
        myt += (t < NB) ? cnt_t[b2*NB + t] : 0;
    if(t < NB) stot[t] = myt;
    __syncthreads();
    if(t == 0){
        int run = 0;
        for(int bb = 0; bb < NB; bb++){
            if(bb == b){ sBase = run; sCnt = stot[bb]; }
            run += stot[bb];
        }
    }
    __syncthreads();
    int base = sBase, cntE = sCnt;
    int n0 = b << BSH;
    int nn = min(1 << BSH, N - n0);

    for(int i = t; i < 1024; i += 256) c[i] = 0;
    __syncthreads();
    for(int i = t; i < cntE; i += 256)
        atomicAdd(&c[pairs[base + i] >> 17], 1);   // LDS atomic
    __syncthreads();
    int i0 = t*4;
    int l0 = c[i0], l1 = c[i0+1], l2 = c[i0+2], l3 = c[i0+3];
    part[t] = l0 + l1 + l2 + l3;
    __syncthreads();
    for(int off = 1; off < 256; off <<= 1){
        int u = (t >= off) ? part[t-off] : 0;
        __syncthreads();
        part[t] += u;
        __syncthreads();
    }
    int run = (t == 0) ? 0 : part[t-1];
    so[i0] = run; so[i0+1] = run + l0; so[i0+2] = run + l0 + l1; so[i0+3] = run + l0 + l1 + l2;
    __syncthreads();
    for(int i = t; i < nn; i += 256){
        int cc = c[i];
        cursor[n0 + i] = base + so[i] + cc;        // inclusive end offset
        dinv[n0 + i]   = rsqrtf((float)(cc + 1));  // +1 = self-loop
        atomicAdd(&dhist[min(cc, DBIN-1)], 1);     // degree histogram (LDS)
    }
    for(int i = t; i < 1024; i += 256) c[i] = so[i];
    __syncthreads();
    if(t < DBIN) dcnt[b*DBIN + t] = dhist[t];
    for(int i = t; i < cntE; i += 256){
        int v = pairs[base + i];
        int pos = atomicAdd(&c[v >> 17], 1);       // LDS atomic
        csrl[pos] = v & 0x1FFFF;
    }
    __syncthreads();
    for(int i = t; i < cntE; i += 256) csr[base + i] = csrl[i];   // coalesced
}

// degree-sort pass 2: turn dcnt[NB][64] counts into scatter bases, in place.
// ordering: bin-major, block-minor -> perm is globally sorted by degree.
__global__ void k_dscan(int* __restrict__ dcnt, int NB){
    __shared__ int binTot[DBIN];
    __shared__ int binBase[DBIN];
    int t = threadIdx.x;
    if(t < DBIN){
        int s = 0;
        for(int b = 0; b < NB; b++) s += dcnt[b*DBIN + t];
        binTot[t] = s;
    }
    __syncthreads();
    if(t == 0){
        int run = 0;
        for(int i = 0; i < DBIN; i++){ binBase[i] = run; run += binTot[i]; }
    }
    __syncthreads();
    if(t < DBIN){
        int run = binBase[t];
        for(int b = 0; b < NB; b++){ int v = dcnt[b*DBIN + t]; dcnt[b*DBIN + t] = run; run += v; }
    }
}

// degree-sort pass 3: perm[pos] = node, bucketed counting scatter (bijective).
__global__ void k_dscatter(const int* __restrict__ cursor, const int* __restrict__ dcnt,
                           int* __restrict__ perm, int N){
    __shared__ int cur[DBIN];
    int b = blockIdx.x, t = threadIdx.x;
    if(t < DBIN) cur[t] = dcnt[b*DBIN + t];
    __syncthreads();
    int n0 = b << BSH;
    int nn = min(1 << BSH, N - n0);
    for(int i = t; i < nn; i += 256){
        int d = n0 + i;
        int deg = cursor[d] - ((d == 0) ? 0 : cursor[d-1]);
        int pos = atomicAdd(&cur[min(deg, DBIN-1)], 1);   // LDS atomic
        perm[pos] = d;
    }
}

// ---------- gather core: self + neighbor sum of one 16B chunk ----------
// R5-bench structure (best measured): 8-wide main loop + single clamped masked
// 8-wide tail batch. Masks exact 0/1 -> bit-identical to serial accumulation.
__device__ inline float8 gather_row(const int* __restrict__ cursor,
                                    const int* __restrict__ csr,
                                    const h8* __restrict__ t, int d, int cg){
    int start = (d == 0) ? 0 : cursor[d-1];
    int end   = cursor[d];
    float8 a0 = h8tof8(t[(size_t)d*6 + cg]);     // self-loop
    float8 a1 = {{0,0,0,0},{0,0,0,0}}, a2 = a1, a3 = a1;
    int j = start;
    for(; j + 8 <= end; j += 8){
        int s0 = csr[j],   s1 = csr[j+1], s2 = csr[j+2], s3 = csr[j+3];
        int s4 = csr[j+4], s5 = csr[j+5], s6 = csr[j+6], s7 = csr[j+7];
        h8 r0 = t[(size_t)s0*6 + cg];            // 8 independent dwordx4 in flight
        h8 r1 = t[(size_t)s1*6 + cg];
        h8 r2 = t[(size_t)s2*6 + cg];
        h8 r3 = t[(size_t)s3*6 + cg];
        h8 r4 = t[(size_t)s4*6 + cg];
        h8 r5 = t[(size_t)s5*6 + cg];
        h8 r6 = t[(size_t)s6*6 + cg];
        h8 r7 = t[(size_t)s7*6 + cg];
        f8acc(a0, h8tof8(r0)); f8acc(a1, h8tof8(r1));
        f8acc(a2, h8tof8(r2)); f8acc(a3, h8tof8(r3));
        f8acc(a0, h8tof8(r4)); f8acc(a1, h8tof8(r5));
        f8acc(a2, h8tof8(r6)); f8acc(a3, h8tof8(r7));
    }
    int rem = end - j;
    if(rem > 0){
        int e1 = end - 1;
        int s0 = csr[j];
        int s1 = csr[min(j+1, e1)], s2 = csr[min(j+2, e1)], s3 = csr[min(j+3, e1)];
        int s4 = csr[min(j+4, e1)], s5 = csr[min(j+5, e1)], s6 = csr[min(j+6, e1)];
        int s7 = csr[min(j+7, e1)];
        h8 r0 = t[(size_t)s0*6 + cg];            // all tail loads in flight together
        h8 r1 = t[(size_t)s1*6 + cg];
        h8 r2 = t[(size_t)s2*6 + cg];
        h8 r3 = t[(size_t)s3*6 + cg];
        h8 r4 = t[(size_t)s4*6 + cg];
        h8 r5 = t[(size_t)s5*6 + cg];
        h8 r6 = t[(size_t)s6*6 + cg];
        h8 r7 = t[(size_t)s7*6 + cg];
        f8acc(a0, h8tof8(r0));                               // k=0 always valid
        f8fma(a1, h8tof8(r1), (1 < rem) ? 1.f : 0.f);
        f8fma(a2, h8tof8(r2), (2 < rem) ? 1.f : 0.f);
        f8fma(a3, h8tof8(r3), (3 < rem) ? 1.f : 0.f);
        f8fma(a0, h8tof8(r4), (4 < rem) ? 1.f : 0.f);
        f8fma(a1, h8tof8(r5), (5 < rem) ? 1.f : 0.f);
        f8fma(a2, h8tof8(r6), (6 < rem) ? 1.f : 0.f);
        f8fma(a3, h8tof8(r7), (7 < rem) ? 1.f : 0.f);
    }
    f8acc(a0, a1); f8acc(a2, a3); f8acc(a0, a2);
    return a0;
}

// ---------- conv1 GEMM, row-batched x4: t = dinv .* (x @ W1) ----------
__global__ void k_gemm1r(const float* __restrict__ x, const float* __restrict__ W,
                         h8* __restrict__ t, int n, const float* __restrict__ dinv){
    __shared__ float sW[44*48];                   // [k][48], zero-padded cols
    for(int i = threadIdx.x; i < 44*48; i += blockDim.x){
        int k = i/48, j = i - k*48;
        sW[i] = (j < 44) ? W[k*44 + j] : 0.f;
    }
    __syncthreads();
    int nrg = (n + 3) >> 2;
    unsigned total = (unsigned)nrg * 6u;
    unsigned idx = blockIdx.x*blockDim.x + threadIdx.x;
    if(idx >= total) return;
    unsigned rg = idx / 6u;
    unsigned cg = idx - rg*6u;
    int row0 = (int)rg*4;
    const float4* sWv = (const float4*)sW;        // 12 float4 per k
    float8 acc[4] = {{{0,0,0,0},{0,0,0,0}},{{0,0,0,0},{0,0,0,0}},
                     {{0,0,0,0},{0,0,0,0}},{{0,0,0,0},{0,0,0,0}}};
    for(int k4 = 0; k4 < 11; k4++){
        float fv[4][4];
        #pragma unroll
        for(int r = 0; r < 4; r++){
            int rr = min(row0 + r, n - 1);        // clamp (tail rows duplicate, store guarded)
            *(float4*)fv[r] = ((const float4*)(x + (size_t)rr*44))[k4];
        }
        int kb = k4*4;
        #pragma unroll
        for(int i = 0; i < 4; i++){
            float4 wlo = sWv[(unsigned)(kb+i)*12 + cg*2];
            float4 whi = sWv[(unsigned)(kb+i)*12 + cg*2 + 1];
            #pragma unroll
            for(int r = 0; r < 4; r++){
                float h = fv[r][i];
                acc[r].lo.x += h*wlo.x; acc[r].lo.y += h*wlo.y;
                acc[r].lo.z += h*wlo.z; acc[r].lo.w += h*wlo.w;
                acc[r].hi.x += h*whi.x; acc[r].hi.y += h*whi.y;
                acc[r].hi.z += h*whi.z; acc[r].hi.w += h*whi.w;
            }
        }
    }
    #pragma unroll
    for(int r = 0; r < 4; r++){
        int row = row0 + r;
        if(row < n){
            float dd = dinv[row];
            acc[r].lo.x *= dd; acc[r].lo.y *= dd; acc[r].lo.z *= dd; acc[r].lo.w *= dd;
            acc[r].hi.x *= dd; acc[r].hi.y *= dd; acc[r].hi.z *= dd; acc[r].hi.w *= dd;
            t[(size_t)row*6 + cg] = f8toh8(acc[r]);
        }
    }
}

// ---------- plain gather (degree-sorted order): d = perm[work] ----------
__global__ void k_gather8(const int* __restrict__ cursor, const int* __restrict__ csr,
                          const h8* __restrict__ t, const float* __restrict__ dinv,
                          const float* __restrict__ bias, const int* __restrict__ perm,
                          h8* __restrict__ out, int n, int prescale_out){
    __shared__ float sb[48];
    if(threadIdx.x < 48) sb[threadIdx.x] = (bias && threadIdx.x < 44) ? bias[threadIdx.x] : 0.f;
    __syncthreads();
    unsigned total  = (unsigned)n * 6u;
    unsigned stride = gridDim.x * blockDim.x;
    const float4* sb4 = (const float4*)sb;
    for(unsigned idx = blockIdx.x*blockDim.x + threadIdx.x; idx < total; idx += stride){
        unsigned w  = idx / 6u;
        unsigned cg = idx - w*6u;
        int d = perm[w];                          // degree-sorted: wave-uniform rounds
        float8 acc = gather_row(cursor, csr, t, d, (int)cg);
        float dd = dinv[d];
        float4 blo = sb4[cg*2], bhi = sb4[cg*2+1];
        acc.lo.x = acc.lo.x*dd + blo.x; acc.lo.y = acc.lo.y*dd + blo.y;
        acc.lo.z = acc.lo.z*dd + blo.z; acc.lo.w = acc.lo.w*dd + blo.w;
        acc.hi.x = acc.hi.x*dd + bhi.x; acc.hi.y = acc.hi.y*dd + bhi.y;
        acc.hi.z = acc.hi.z*dd + bhi.z; acc.hi.w = acc.hi.w*dd + bhi.w;
        if(bias){
            acc.lo.x = fmaxf(acc.lo.x, 0.f); acc.lo.y = fmaxf(acc.lo.y, 0.f);
            acc.lo.z = fmaxf(acc.lo.z, 0.f); acc.lo.w = fmaxf(acc.lo.w, 0.f);
            acc.hi.x = fmaxf(acc.hi.x, 0.f); acc.hi.y = fmaxf(acc.hi.y, 0.f);
            acc.hi.z = fmaxf(acc.hi.z, 0.f); acc.hi.w = fmaxf(acc.hi.w, 0.f);
        }
        if(prescale_out){
            acc.lo.x *= dd; acc.lo.y *= dd; acc.lo.z *= dd; acc.lo.w *= dd;
            acc.hi.x *= dd; acc.hi.y *= dd; acc.hi.z *= dd; acc.hi.w *= dd;
        }
        out[(size_t)d*6 + cg] = f8toh8(acc);      // scattered 96B store (minor)
    }
}

// ---------- fused conv3-aggregate + global max pool (identity order) ----------
__global__ void k_gather_pool(const int* __restrict__ cursor, const int* __restrict__ csr,
                              const h8* __restrict__ t, const float* __restrict__ dinv,
                              const float* __restrict__ bias, const int* __restrict__ batch,
                              float* __restrict__ pooled, int n){
    __shared__ float sb[48];
    __shared__ unsigned spool[3*48];             // NPP=42 nodes span <=2 graphs; 3 for safety
    int tid = threadIdx.x;
    if(tid < 48) sb[tid] = (tid < 44) ? bias[tid] : 0.f;
    for(int i = tid; i < 3*48; i += 256) spool[i] = 0u;
    int d0 = blockIdx.x*NPP;
    __syncthreads();
    int g0 = batch[d0];
    int tasks = min(NPP, n - d0)*6;
    const float4* sb4 = (const float4*)sb;
    for(int o = tid; o < tasks; o += 256){
        int ln = o/6, cg = o - ln*6;
        int d = d0 + ln;
        float8 acc = gather_row(cursor, csr, t, d, cg);
        float dd = dinv[d];
        float4 blo = sb4[cg*2], bhi = sb4[cg*2+1];
        acc.lo.x = fmaxf(acc.lo.x*dd + blo.x, 0.f); acc.lo.y = fmaxf(acc.lo.y*dd + blo.y, 0.f);
        acc.lo.z = fmaxf(acc.lo.z*dd + blo.z, 0.f); acc.lo.w = fmaxf(acc.lo.w*dd + blo.w, 0.f);
        acc.hi.x = fmaxf(acc.hi.x*dd + bhi.x, 0.f); acc.hi.y = fmaxf(acc.hi.y*dd + bhi.y, 0.f);
        acc.hi.z = fmaxf(acc.hi.z*dd + bhi.z, 0.f); acc.hi.w = fmaxf(acc.hi.w*dd + bhi.w, 0.f);
        int gi = batch[d] - g0;                  // 0..2
        unsigned* sp = spool + gi*48 + cg*8;
        atomicMax(&sp[0], __float_as_uint(acc.lo.x));
        atomicMax(&sp[1], __float_as_uint(acc.lo.y));
        atomicMax(&sp[2], __float_as_uint(acc.lo.z));
        atomicMax(&sp[3], __float_as_uint(acc.lo.w));
        atomicMax(&sp[4], __float_as_uint(acc.hi.x));
        atomicMax(&sp[5], __float_as_uint(acc.hi.y));
        atomicMax(&sp[6], __float_as_uint(acc.hi.z));
        atomicMax(&sp[7], __float_as_uint(acc.hi.w));
    }
    __syncthreads();
    for(int i = tid; i < 3*48; i += 256){
        unsigned v = spool[i];
        if(v) atomicMax((unsigned*)&pooled[(size_t)(g0 + i/48)*48 + (i - (i/48)*48)], v);
    }
}

// ---------- fused conv2 + conv3-transform (MFMA; degree-sorted node blocks) ----------
__global__ void k_gconv2(const int* __restrict__ cursor, const int* __restrict__ csr,
                         const h8* __restrict__ tin, const float* __restrict__ dinv,
                         const float* __restrict__ W2, const float* __restrict__ b2,
                         const float* __restrict__ W3, const int* __restrict__ perm,
                         h8* __restrict__ tout, int N){
    __shared__ __align__(16) _Float16 sW[96*72];    // GEMM1: W2^T [96 col][72 k]; GEMM2: W3^T [48 col][104 k]
    __shared__ __align__(16) _Float16 sH2[48*104];  // H2 [48 row][104 k] (k 0..95 valid)
    __shared__ __align__(16) _Float16 sAgg[48*72];  // GEMM1 A [48 row][72 k]; reused as T3 [48 row][72]
    __shared__ float sb2[96];
    __shared__ float sDinv[48];
    __shared__ int   sPerm[48];
    int t  = threadIdx.x;
    int d0 = blockIdx.x*NPB;
    int nn = min(NPB, N - d0);

    // stage W2^T (zero-padded) + b2 + zero sAgg/sDinv (pads must be exactly 0)
    {
        int* z = (int*)sAgg;                       // 48*72 halves = 1728 dwords
        for(int i = t; i < 1728; i += 256) z[i] = 0;
        if(t < 96) sb2[t] = (t < 88) ? b2[t] : 0.f;
        if(t < 48) sDinv[t] = 0.f;
        for(int i = t; i < 96*72; i += 256){
            int c = i/72, k = i - c*72;
            sW[i] = (_Float16)((c < 88 && k < 44) ? W2[k*88 + c] : 0.f);
        }
    }
    __syncthreads();

    // phase 1: gather (6 threads per node, nodes = perm[d0..d0+nn)) -> sAgg f16
    int ln = t/6, c = t - ln*6;
    if(t < NPB*6 && ln < nn){
        int d = perm[d0 + ln];                     // similar-degree nodes per block
        float8 acc = gather_row(cursor, csr, tin, d, c);
        float dd = dinv[d];
        if(c == 0){ sDinv[ln] = dd; sPerm[ln] = d; }
        acc.lo.x *= dd; acc.lo.y *= dd; acc.lo.z *= dd; acc.lo.w *= dd;
        acc.hi.x *= dd; acc.hi.y *= dd; acc.hi.z *= dd; acc.hi.w *= dd;
        *(h8*)(sAgg + ln*72 + c*8) = f8toh8(acc);
    }
    __syncthreads();

    int w  = t >> 6;
    int l  = t & 63;
    int lr = l & 15;          // A-row / B-col / D-col within tile
    int lk = l >> 4;          // k-group (8 contiguous k per fragment)

    // phase 2 (GEMM1): H2 = relu(A @ W2 + b2); 18 tiles (3 mi x 6 ni), K=64 padded
    for(int tile = w; tile < 18; tile += 4){
        int mi = tile/6, ni = tile - mi*6;
        f16x8_t a0 = *(const f16x8_t*)(sAgg + (mi*16 + lr)*72 + lk*8);
        f16x8_t a1 = *(const f16x8_t*)(sAgg + (mi*16 + lr)*72 + 32 + lk*8);
        f16x8_t b0 = *(const f16x8_t*)(sW   + (ni*16 + lr)*72 + lk*8);
        f16x8_t b1 = *(const f16x8_t*)(sW   + (ni*16 + lr)*72 + 32 + lk*8);
        f32x4_t acc = {0.f, 0.f, 0.f, 0.f};
        acc = __builtin_amdgcn_mfma_f32_16x16x32_f16(a0, b0, acc, 0, 0, 0);
        acc = __builtin_amdgcn_mfma_f32_16x16x32_f16(a1, b1, acc, 0, 0, 0);
        int col = ni*16 + lr;
        float bb = sb2[col];
        int r0 = mi*16 + lk*4;
        #pragma unroll
        for(int r = 0; r < 4; r++)
            sH2[(r0 + r)*104 + col] = (_Float16)fmaxf(acc[r] + bb, 0.f);
    }
    __syncthreads();

    // restage W3^T [48 col][104 k] (zero-padded; pads MUST be 0: cols 44..47 are stored)
    for(int i = t; i < 48*104; i += 256){
        int cc_ = i/104, k = i - cc_*104;
        sW[i] = (_Float16)((cc_ < 44 && k < 88) ? W3[k*44 + cc_] : 0.f);
    }
    __syncthreads();

    // phase 3 (GEMM2): T3 = dinv .* (H2 @ W3); 9 tiles (3 mi x 3 ni), K=96 exact
    for(int tile = w; tile < 9; tile += 4){
        int mi = tile/3, ni = tile - mi*3;
        f32x4_t acc = {0.f, 0.f, 0.f, 0.f};
        #pragma unroll
        for(int ks = 0; ks < 3; ks++){
            f16x8_t a = *(const f16x8_t*)(sH2 + (mi*16 + lr)*104 + ks*32 + lk*8);
            f16x8_t b = *(const f16x8_t*)(sW  + (ni*16 + lr)*104 + ks*32 + lk*8);
            acc = __builtin_amdgcn_mfma_f32_16x16x32_f16(a, b, acc, 0, 0, 0);
        }
        int col = ni*16 + lr;
        int r0 = mi*16 + lk*4;
        #pragma unroll
        for(int r = 0; r < 4; r++)
            sAgg[(r0 + r)*72 + col] = (_Float16)(acc[r]*sDinv[r0 + r]);  // T3 into sAgg buffer
    }
    __syncthreads();

    // final: h8 stores of real rows (scattered by perm)
    for(int o = t; o < nn*6; o += 256){
        int n_ = o/6, cc = o - n_*6;
        tout[(size_t)sPerm[n_]*6 + cc] = *(const h8*)(sAgg + n_*72 + cc*8);
    }
}

// tiny epilogue: 4 graphs/block (one wave each), reads pooled[G][48]
__global__ void k_headfin(const float* __restrict__ pooled, const float* __restrict__ partial,
                          const float* __restrict__ bf1, const float* __restrict__ Wf2,
                          const float* __restrict__ bf2, const float* __restrict__ Wg,
                          const float* __restrict__ bg, float* __restrict__ out,
                          int G, int H){
    int g    = blockIdx.x*4 + (threadIdx.x >> 6);
    int lane = threadIdx.x & 63;

    // x1 partial dot: lanes 0..43 each one feature
    float v = 0.f;
    if(lane < 44) v = pooled[(size_t)g*48 + lane]*Wg[lane];

    // x2: combine split-K partials
    float2 s = {0.f, 0.f};
    for(int ks = 0; ks < KS; ks++){
        float2 p = ((const float2*)(partial + ((size_t)ks*G + g)*H))[lane];
        s.x += p.x; s.y += p.y;
    }
    float2 b  = ((const float2*)bf1)[lane];
    float2 w2 = ((const float2*)Wf2)[lane];
    float y = fmaxf(s.x + b.x, 0.f)*w2.x + fmaxf(s.y + b.y, 0.f)*w2.y;

    for(int off = 32; off; off >>= 1){
        y += __shfl_xor(y, off, 64);
        v += __shfl_xor(v, off, 64);
    }
    if(lane == 0) out[g] = fmaxf(v + bg[0], 0.f) + y + bf2[0];
}

extern "C" void kernel_launch(void* const* d_in, const int* in_sizes, int n_in,
                              void* d_out, int out_size, void* d_ws, size_t ws_size,
                              hipStream_t stream) {
    const float* x       = (const float*)d_in[0];
    const int*   ei      = (const int*)  d_in[1];
    const int*   batch   = (const int*)  d_in[2];
    const float* feature = (const float*)d_in[3];
    const float* W1 = (const float*)d_in[4];  const float* b1 = (const float*)d_in[5];
    const float* W2 = (const float*)d_in[6];  const float* b2 = (const float*)d_in[7];
    const float* W3 = (const float*)d_in[8];  const float* b3 = (const float*)d_in[9];
    const float* Wg = (const float*)d_in[10]; const float* bg = (const float*)d_in[11];
    const float* Wf1= (const float*)d_in[12]; const float* bf1= (const float*)d_in[13];
    const float* Wf2= (const float*)d_in[14]; const float* bf2= (const float*)d_in[15];
    float* out = (float*)d_out;

    const int N    = in_sizes[2];          // 100000 (< 2^17 required by pair packing)
    const int E    = in_sizes[1] / 2;      // 1000000
    const int G    = out_size;             // 1024
    const int FEAT = in_sizes[3] / G;      // 1019
    const int H    = in_sizes[13];         // 128

    const int NB    = cdiv(N, 1 << BSH);   // 98 coarse buckets
    const int chunk = cdiv(E, NBLK1);
    const int NRG   = cdiv(N, 4);

    // workspace layout (4B units)
    float* wsf    = (float*)d_ws;
    float* dinv   = wsf;                          // N floats
    int*   cursor = (int*)(dinv + N);             // N ints
    int*   csr    = cursor + N;                   // E ints
    h8*    bufA   = (h8*)(csr + E);               // N*6 h8
    h8*    bufC   = bufA + (size_t)N*6;           // N*6 h8
    float* partial= (float*)(bufC + (size_t)N*6); // KS*G*H floats
    float* scratch= partial + (size_t)KS*G*H;
    int*   pairs  = (int*)scratch;                // E ints (packed; CSR build)
    int*   cnt_t  = pairs + E;                    // NBLK1*NB ints
    float* pooled = (float*)(cnt_t + NBLK1*NB);   // G*48 floats
    int*   dcnt   = (int*)(pooled + (size_t)G*48);// NB*DBIN ints (degree-sort)
    int*   perm   = dcnt + NB*DBIN;               // N ints

    // ---- kernel 1: bucket count + head split-K GEMM (independent, merged) ----
    k_bcnt_head<<<NBLK1 + (G/GB)*KS, TPB, 0, stream>>>(
        ei + E, cnt_t, E, NB, chunk, feature, Wf1, partial, G, FEAT, H);

    // ---- CSR build (bscatter also zeroes pooled; build also emits degree hist) ----
    k_bscatter<<<NBLK1, TPB, 0, stream>>>(ei, cnt_t, pairs, E, NB, chunk, pooled, G);
    k_build   <<<NB, TPB, 0, stream>>>(pairs, cnt_t, csr, cursor, dinv, dcnt, N, E, NB);

    // ---- degree sort: perm = nodes sorted by degree (bijective, correctness-neutral) ----
    k_dscan   <<<1, TPB, 0, stream>>>(dcnt, NB);
    k_dscatter<<<NB, TPB, 0, stream>>>(cursor, dcnt, perm, N);

    // ---- conv1: bufA = dinv.*(x@W1) ; bufC = dinv.*relu(dinv*agg + b1) ----
    k_gemm1r <<<cdiv((long long)NRG*6, TPB), TPB, 0, stream>>>(x, W1, bufA, N, dinv);
    k_gather8<<<cdiv((long long)N*6, TPB), TPB, 0, stream>>>(cursor, csr, bufA, dinv, b1,
                                                             perm, bufC, N, 1);

    // ---- conv2 + conv3-transform fused (MFMA) ----
    k_gconv2 <<<cdiv(N, NPB), TPB, 0, stream>>>(cursor, csr, bufC, dinv, W2, b2, W3,
                                                perm, bufA, N);

    // ---- conv3 aggregate + pool fused (identity order: graph-local pooling) ----
    k_gather_pool<<<cdiv(N, NPP), TPB, 0, stream>>>(cursor, csr, bufA, dinv, b3, batch,
                                                    pooled, N);

    // ---- head epilogue ----
    k_headfin<<<G/4, 256, 0, stream>>>(pooled, partial, bf1, Wf2, bf2, Wg, bg, out, G, H);
}

// Round 9
// 297.944 us; speedup vs baseline: 1.0798x; 1.0798x over previous
//
#include <hip/hip_runtime.h>
#include <hip/hip_fp16.h>

#define TPB 256
#define NBLK1 256          // CSR pass-1 blocks
#define BSH 10             // bucket shift: 1024 nodes per bucket (NB <= 128)
#define MAXBE 12288        // max edges/bucket -> 48KB LDS
#define KS 8               // head GEMM K-splits
#define GB 8               // head GEMM graphs per block
#define NPB 42             // gconv2 nodes/block (42*6 = 252 <= 256)
#define NPP 42             // gather_pool nodes/block (252 tasks -> 1/thread)
#define DBIN 64            // degree-sort bins

static inline int cdiv(long long a, int b){ return (int)((a + b - 1)/b); }

typedef _Float16 f16x8_t __attribute__((ext_vector_type(8)));
typedef float    f32x4_t __attribute__((ext_vector_type(4)));

// 8 halves = 16 bytes, 16-byte aligned -> single dwordx4 loads
struct __align__(16) h8 { __half2 a, b, c, d; };
struct float8 { float4 lo, hi; };
__device__ inline float8 h8tof8(h8 v){
    float2 t0 = __half22float2(v.a), t1 = __half22float2(v.b);
    float2 t2 = __half22float2(v.c), t3 = __half22float2(v.d);
    float8 r;
    r.lo = make_float4(t0.x, t0.y, t1.x, t1.y);
    r.hi = make_float4(t2.x, t2.y, t3.x, t3.y);
    return r;
}
__device__ inline h8 f8toh8(float8 v){
    h8 r;
    r.a = __floats2half2_rn(v.lo.x, v.lo.y); r.b = __floats2half2_rn(v.lo.z, v.lo.w);
    r.c = __floats2half2_rn(v.hi.x, v.hi.y); r.d = __floats2half2_rn(v.hi.z, v.hi.w);
    return r;
}
__device__ inline void f8acc(float8& a, float8 v){
    a.lo.x += v.lo.x; a.lo.y += v.lo.y; a.lo.z += v.lo.z; a.lo.w += v.lo.w;
    a.hi.x += v.hi.x; a.hi.y += v.hi.y; a.hi.z += v.hi.z; a.hi.w += v.hi.w;
}
__device__ inline void f8fma(float8& a, float8 v, float m){
    a.lo.x = fmaf(v.lo.x, m, a.lo.x); a.lo.y = fmaf(v.lo.y, m, a.lo.y);
    a.lo.z = fmaf(v.lo.z, m, a.lo.z); a.lo.w = fmaf(v.lo.w, m, a.lo.w);
    a.hi.x = fmaf(v.hi.x, m, a.hi.x); a.hi.y = fmaf(v.hi.y, m, a.hi.y);
    a.hi.z = fmaf(v.hi.z, m, a.hi.z); a.hi.w = fmaf(v.hi.w, m, a.hi.w);
}

// ---------- kernel 1: bucket count (blocks 0..NBLK1) + head split-K GEMM (rest) ----------
__global__ void k_bcnt_head(const int* __restrict__ dst, int* __restrict__ cnt_t,
                            int E, int NB, int chunk,
                            const float* __restrict__ feature, const float* __restrict__ Wf1,
                            float* __restrict__ partial, int G, int FEAT, int H){
    __shared__ int hist[128];
    __shared__ float sfeat[128*GB];
    int t = threadIdx.x;
    if(blockIdx.x < NBLK1){
        // ---- bucket count ----
        int blk = blockIdx.x;
        for(int i = t; i < NB; i += blockDim.x) hist[i] = 0;
        __syncthreads();
        int lo = blk*chunk, hi = min(E, lo + chunk);
        for(int e = lo + t; e < hi; e += blockDim.x)
            atomicAdd(&hist[dst[e] >> BSH], 1);
        __syncthreads();
        for(int b = t; b < NB; b += blockDim.x)
            cnt_t[blk*NB + b] = hist[b];
    } else {
        // ---- head split-K GEMM: partial[ks][g][h] ----
        int bid = (int)blockIdx.x - NBLK1;          // 0..1023
        int g0 = (bid & 127)*GB;
        int ks = bid >> 7;
        int Kc = (FEAT + KS - 1)/KS;
        int k0 = ks*Kc;
        int k1 = min(FEAT, k0 + Kc);
        int kc = k1 - k0;
        for(int idx = t; idx < GB*128; idx += 256){
            int gi = idx >> 7, kk = idx & 127;
            if(kk < kc) sfeat[kk*GB + gi] = feature[(size_t)(g0+gi)*FEAT + k0 + kk];
        }
        __syncthreads();
        int h  = t & 127;
        int gq = t >> 7;
        const float* wp = Wf1 + (size_t)k0*H + h;
        float4 a = {0.f,0.f,0.f,0.f};
        const float4* sf = (const float4*)(sfeat) + gq;
        for(int kk = 0; kk < kc; kk++){
            float w = wp[(size_t)kk*H];
            float4 f = sf[kk*2];
            a.x += f.x*w; a.y += f.y*w; a.z += f.z*w; a.w += f.w*w;
        }
        float* pp = partial + ((size_t)ks*G + g0 + gq*4)*H + h;
        pp[0] = a.x; pp[H] = a.y; pp[2*H] = a.z; pp[3*H] = a.w;
    }
}

// scatter with inline prefix: pairs[pos] = (local_dst<<17)|src  (needs N < 2^17)
// also zeroes pooled[G*48] (65536 threads >= 49152 elems; stream-ordered before use)
__global__ void k_bscatter(const int* __restrict__ ei, const int* __restrict__ cnt_t,
                           int* __restrict__ pairs, int E, int NB, int chunk,
                           float* __restrict__ pooled, int G){
    __shared__ int cur[128];
    __shared__ int st[128];
    int blk = blockIdx.x;
    int t = threadIdx.x;
    int zi = blk*256 + t;
    if(zi < G*48) pooled[zi] = 0.f;
    int myp = 0, myt = 0;
    for(int b2 = 0; b2 < NBLK1; b2++){
        int v = (t < NB) ? cnt_t[b2*NB + t] : 0;
        myp += (b2 < blk) ? v : 0;
        myt += v;
    }
    if(t < NB){ cur[t] = myp; st[t] = myt; }
    __syncthreads();
    if(t == 0){
        int run = 0;
        for(int b = 0; b < NB; b++){ int v = st[b]; st[b] = run; run += v; }
    }
    __syncthreads();
    if(t < NB) cur[t] += st[t];
    __syncthreads();
    int lo = blk*chunk, hi = min(E, lo + chunk);
    for(int e = lo + t; e < hi; e += blockDim.x){
        int s = ei[e], d = ei[E + e];
        int pos = atomicAdd(&cur[d >> BSH], 1);          // LDS atomic
        pairs[pos] = ((d & ((1 << BSH) - 1)) << 17) | s; // packed
    }
}

// R8b: also emits BUCKET-LOCAL degree-sorted perm (perm[n0..n0+nn) = bucket's
// nodes sorted by degree). Keeps all gather accesses within a 96KB L2 window
// while making waves degree-uniform. Bijective -> arithmetic-neutral.
__global__ void k_build(const int* __restrict__ pairs, const int* __restrict__ cnt_t,
                        int* __restrict__ csr, int* __restrict__ cursor,
                        float* __restrict__ dinv, int* __restrict__ perm,
                        int N, int E, int NB){
    __shared__ int stot[128];
    __shared__ int sBase, sCnt;
    __shared__ int c[1024];
    __shared__ int so[1024];
    __shared__ int part[256];
    __shared__ int dbase[DBIN];
    __shared__ int csrl[MAXBE];
    int b = blockIdx.x;
    int t = threadIdx.x;
    if(t < DBIN) dbase[t] = 0;
    int myt = 0;
    for(int b2 = 0; b2 < NBLK1; b2++)
        myt += (t < NB) ? cnt_t[b2*NB + t] : 0;
    if(t < NB) stot[t] = myt;
    __syncthreads();
    if(t == 0){
        int run = 0;
        for(int bb = 0; bb < NB; bb++){
            if(bb == b){ sBase = run; sCnt = stot[bb]; }
            run += stot[bb];
        }
    }
    __syncthreads();
    int base = sBase, cntE = sCnt;
    int n0 = b << BSH;
    int nn = min(1 << BSH, N - n0);

    for(int i = t; i < 1024; i += 256) c[i] = 0;
    __syncthreads();
    for(int i = t; i < cntE; i += 256)
        atomicAdd(&c[pairs[base + i] >> 17], 1);   // LDS atomic
    __syncthreads();
    int i0 = t*4;
    int l0 = c[i0], l1 = c[i0+1], l2 = c[i0+2], l3 = c[i0+3];
    part[t] = l0 + l1 + l2 + l3;
    __syncthreads();
    for(int off = 1; off < 256; off <<= 1){
        int u = (t >= off) ? part[t-off] : 0;
        __syncthreads();
        part[t] += u;
        __syncthreads();
    }
    int run = (t == 0) ? 0 : part[t-1];
    so[i0] = run; so[i0+1] = run + l0; so[i0+2] = run + l0 + l1; so[i0+3] = run + l0 + l1 + l2;
    __syncthreads();
    for(int i = t; i < nn; i += 256){
        int cc = c[i];
        cursor[n0 + i] = base + so[i] + cc;        // inclusive end offset
        dinv[n0 + i]   = rsqrtf((float)(cc + 1));  // +1 = self-loop
        atomicAdd(&dbase[min(cc, DBIN-1)], 1);     // degree histogram (LDS)
    }
    __syncthreads();
    if(t == 0){                                    // bucket-local prefix of 64 bins
        int run2 = 0;
        for(int i = 0; i < DBIN; i++){ int v = dbase[i]; dbase[i] = run2; run2 += v; }
    }
    __syncthreads();
    for(int i = t; i < nn; i += 256){              // counting scatter (c[] still = degree)
        int pos = atomicAdd(&dbase[min(c[i], DBIN-1)], 1);
        perm[n0 + pos] = n0 + i;
    }
    __syncthreads();
    for(int i = t; i < 1024; i += 256) c[i] = so[i];
    __syncthreads();
    for(int i = t; i < cntE; i += 256){
        int v = pairs[base + i];
        int pos = atomicAdd(&c[v >> 17], 1);       // LDS atomic
        csrl[pos] = v & 0x1FFFF;
    }
    __syncthreads();
    for(int i = t; i < cntE; i += 256) csr[base + i] = csrl[i];   // coalesced
}

// ---------- gather core: self + neighbor sum of one 16B chunk ----------
// R5-bench structure (best measured): 8-wide main loop + single clamped masked
// 8-wide tail batch. Masks exact 0/1 -> bit-identical to serial accumulation.
__device__ inline float8 gather_row(const int* __restrict__ cursor,
                                    const int* __restrict__ csr,
                                    const h8* __restrict__ t, int d, int cg){
    int start = (d == 0) ? 0 : cursor[d-1];
    int end   = cursor[d];
    float8 a0 = h8tof8(t[(size_t)d*6 + cg]);     // self-loop
    float8 a1 = {{0,0,0,0},{0,0,0,0}}, a2 = a1, a3 = a1;
    int j = start;
    for(; j + 8 <= end; j += 8){
        int s0 = csr[j],   s1 = csr[j+1], s2 = csr[j+2], s3 = csr[j+3];
        int s4 = csr[j+4], s5 = csr[j+5], s6 = csr[j+6], s7 = csr[j+7];
        h8 r0 = t[(size_t)s0*6 + cg];            // 8 independent dwordx4 in flight
        h8 r1 = t[(size_t)s1*6 + cg];
        h8 r2 = t[(size_t)s2*6 + cg];
        h8 r3 = t[(size_t)s3*6 + cg];
        h8 r4 = t[(size_t)s4*6 + cg];
        h8 r5 = t[(size_t)s5*6 + cg];
        h8 r6 = t[(size_t)s6*6 + cg];
        h8 r7 = t[(size_t)s7*6 + cg];
        f8acc(a0, h8tof8(r0)); f8acc(a1, h8tof8(r1));
        f8acc(a2, h8tof8(r2)); f8acc(a3, h8tof8(r3));
        f8acc(a0, h8tof8(r4)); f8acc(a1, h8tof8(r5));
        f8acc(a2, h8tof8(r6)); f8acc(a3, h8tof8(r7));
    }
    int rem = end - j;
    if(rem > 0){
        int e1 = end - 1;
        int s0 = csr[j];
        int s1 = csr[min(j+1, e1)], s2 = csr[min(j+2, e1)], s3 = csr[min(j+3, e1)];
        int s4 = csr[min(j+4, e1)], s5 = csr[min(j+5, e1)], s6 = csr[min(j+6, e1)];
        int s7 = csr[min(j+7, e1)];
        h8 r0 = t[(size_t)s0*6 + cg];            // all tail loads in flight together
        h8 r1 = t[(size_t)s1*6 + cg];
        h8 r2 = t[(size_t)s2*6 + cg];
        h8 r3 = t[(size_t)s3*6 + cg];
        h8 r4 = t[(size_t)s4*6 + cg];
        h8 r5 = t[(size_t)s5*6 + cg];
        h8 r6 = t[(size_t)s6*6 + cg];
        h8 r7 = t[(size_t)s7*6 + cg];
        f8acc(a0, h8tof8(r0));                               // k=0 always valid
        f8fma(a1, h8tof8(r1), (1 < rem) ? 1.f : 0.f);
        f8fma(a2, h8tof8(r2), (2 < rem) ? 1.f : 0.f);
        f8fma(a3, h8tof8(r3), (3 < rem) ? 1.f : 0.f);
        f8fma(a0, h8tof8(r4), (4 < rem) ? 1.f : 0.f);
        f8fma(a1, h8tof8(r5), (5 < rem) ? 1.f : 0.f);
        f8fma(a2, h8tof8(r6), (6 < rem) ? 1.f : 0.f);
        f8fma(a3, h8tof8(r7), (7 < rem) ? 1.f : 0.f);
    }
    f8acc(a0, a1); f8acc(a2, a3); f8acc(a0, a2);
    return a0;
}

// ---------- conv1 GEMM, row-batched x4: t = dinv .* (x @ W1) ----------
__global__ void k_gemm1r(const float* __restrict__ x, const float* __restrict__ W,
                         h8* __restrict__ t, int n, const float* __restrict__ dinv){
    __shared__ float sW[44*48];                   // [k][48], zero-padded cols
    for(int i = threadIdx.x; i < 44*48; i += blockDim.x){
        int k = i/48, j = i - k*48;
        sW[i] = (j < 44) ? W[k*44 + j] : 0.f;
    }
    __syncthreads();
    int nrg = (n + 3) >> 2;
    unsigned total = (unsigned)nrg * 6u;
    unsigned idx = blockIdx.x*blockDim.x + threadIdx.x;
    if(idx >= total) return;
    unsigned rg = idx / 6u;
    unsigned cg = idx - rg*6u;
    int row0 = (int)rg*4;
    const float4* sWv = (const float4*)sW;        // 12 float4 per k
    float8 acc[4] = {{{0,0,0,0},{0,0,0,0}},{{0,0,0,0},{0,0,0,0}},
                     {{0,0,0,0},{0,0,0,0}},{{0,0,0,0},{0,0,0,0}}};
    for(int k4 = 0; k4 < 11; k4++){
        float fv[4][4];
        #pragma unroll
        for(int r = 0; r < 4; r++){
            int rr = min(row0 + r, n - 1);        // clamp (tail rows duplicate, store guarded)
            *(float4*)fv[r] = ((const float4*)(x + (size_t)rr*44))[k4];
        }
        int kb = k4*4;
        #pragma unroll
        for(int i = 0; i < 4; i++){
            float4 wlo = sWv[(unsigned)(kb+i)*12 + cg*2];
            float4 whi = sWv[(unsigned)(kb+i)*12 + cg*2 + 1];
            #pragma unroll
            for(int r = 0; r < 4; r++){
                float h = fv[r][i];
                acc[r].lo.x += h*wlo.x; acc[r].lo.y += h*wlo.y;
                acc[r].lo.z += h*wlo.z; acc[r].lo.w += h*wlo.w;
                acc[r].hi.x += h*whi.x; acc[r].hi.y += h*whi.y;
                acc[r].hi.z += h*whi.z; acc[r].hi.w += h*whi.w;
            }
        }
    }
    #pragma unroll
    for(int r = 0; r < 4; r++){
        int row = row0 + r;
        if(row < n){
            float dd = dinv[row];
            acc[r].lo.x *= dd; acc[r].lo.y *= dd; acc[r].lo.z *= dd; acc[r].lo.w *= dd;
            acc[r].hi.x *= dd; acc[r].hi.y *= dd; acc[r].hi.z *= dd; acc[r].hi.w *= dd;
            t[(size_t)row*6 + cg] = f8toh8(acc[r]);
        }
    }
}

// ---------- plain gather (bucket-local degree-sorted order): d = perm[work] ----------
__global__ void k_gather8(const int* __restrict__ cursor, const int* __restrict__ csr,
                          const h8* __restrict__ t, const float* __restrict__ dinv,
                          const float* __restrict__ bias, const int* __restrict__ perm,
                          h8* __restrict__ out, int n, int prescale_out){
    __shared__ float sb[48];
    if(threadIdx.x < 48) sb[threadIdx.x] = (bias && threadIdx.x < 44) ? bias[threadIdx.x] : 0.f;
    __syncthreads();
    unsigned total  = (unsigned)n * 6u;
    unsigned stride = gridDim.x * blockDim.x;
    const float4* sb4 = (const float4*)sb;
    for(unsigned idx = blockIdx.x*blockDim.x + threadIdx.x; idx < total; idx += stride){
        unsigned w  = idx / 6u;
        unsigned cg = idx - w*6u;
        int d = perm[w];                          // degree-uniform wave, bucket-local
        float8 acc = gather_row(cursor, csr, t, d, (int)cg);
        float dd = dinv[d];
        float4 blo = sb4[cg*2], bhi = sb4[cg*2+1];
        acc.lo.x = acc.lo.x*dd + blo.x; acc.lo.y = acc.lo.y*dd + blo.y;
        acc.lo.z = acc.lo.z*dd + blo.z; acc.lo.w = acc.lo.w*dd + blo.w;
        acc.hi.x = acc.hi.x*dd + bhi.x; acc.hi.y = acc.hi.y*dd + bhi.y;
        acc.hi.z = acc.hi.z*dd + bhi.z; acc.hi.w = acc.hi.w*dd + bhi.w;
        if(bias){
            acc.lo.x = fmaxf(acc.lo.x, 0.f); acc.lo.y = fmaxf(acc.lo.y, 0.f);
            acc.lo.z = fmaxf(acc.lo.z, 0.f); acc.lo.w = fmaxf(acc.lo.w, 0.f);
            acc.hi.x = fmaxf(acc.hi.x, 0.f); acc.hi.y = fmaxf(acc.hi.y, 0.f);
            acc.hi.z = fmaxf(acc.hi.z, 0.f); acc.hi.w = fmaxf(acc.hi.w, 0.f);
        }
        if(prescale_out){
            acc.lo.x *= dd; acc.lo.y *= dd; acc.lo.z *= dd; acc.lo.w *= dd;
            acc.hi.x *= dd; acc.hi.y *= dd; acc.hi.z *= dd; acc.hi.w *= dd;
        }
        out[(size_t)d*6 + cg] = f8toh8(acc);      // store within bucket window
    }
}

// ---------- fused conv3-aggregate + global max pool (identity order) ----------
__global__ void k_gather_pool(const int* __restrict__ cursor, const int* __restrict__ csr,
                              const h8* __restrict__ t, const float* __restrict__ dinv,
                              const float* __restrict__ bias, const int* __restrict__ batch,
                              float* __restrict__ pooled, int n){
    __shared__ float sb[48];
    __shared__ unsigned spool[3*48];             // NPP=42 nodes span <=2 graphs; 3 for safety
    int tid = threadIdx.x;
    if(tid < 48) sb[tid] = (tid < 44) ? bias[tid] : 0.f;
    for(int i = tid; i < 3*48; i += 256) spool[i] = 0u;
    int d0 = blockIdx.x*NPP;
    __syncthreads();
    int g0 = batch[d0];
    int tasks = min(NPP, n - d0)*6;
    const float4* sb4 = (const float4*)sb;
    for(int o = tid; o < tasks; o += 256){
        int ln = o/6, cg = o - ln*6;
        int d = d0 + ln;
        float8 acc = gather_row(cursor, csr, t, d, cg);
        float dd = dinv[d];
        float4 blo = sb4[cg*2], bhi = sb4[cg*2+1];
        acc.lo.x = fmaxf(acc.lo.x*dd + blo.x, 0.f); acc.lo.y = fmaxf(acc.lo.y*dd + blo.y, 0.f);
        acc.lo.z = fmaxf(acc.lo.z*dd + blo.z, 0.f); acc.lo.w = fmaxf(acc.lo.w*dd + blo.w, 0.f);
        acc.hi.x = fmaxf(acc.hi.x*dd + bhi.x, 0.f); acc.hi.y = fmaxf(acc.hi.y*dd + bhi.y, 0.f);
        acc.hi.z = fmaxf(acc.hi.z*dd + bhi.z, 0.f); acc.hi.w = fmaxf(acc.hi.w*dd + bhi.w, 0.f);
        int gi = batch[d] - g0;                  // 0..2
        unsigned* sp = spool + gi*48 + cg*8;
        atomicMax(&sp[0], __float_as_uint(acc.lo.x));
        atomicMax(&sp[1], __float_as_uint(acc.lo.y));
        atomicMax(&sp[2], __float_as_uint(acc.lo.z));
        atomicMax(&sp[3], __float_as_uint(acc.lo.w));
        atomicMax(&sp[4], __float_as_uint(acc.hi.x));
        atomicMax(&sp[5], __float_as_uint(acc.hi.y));
        atomicMax(&sp[6], __float_as_uint(acc.hi.z));
        atomicMax(&sp[7], __float_as_uint(acc.hi.w));
    }
    __syncthreads();
    for(int i = tid; i < 3*48; i += 256){
        unsigned v = spool[i];
        if(v) atomicMax((unsigned*)&pooled[(size_t)(g0 + i/48)*48 + (i - (i/48)*48)], v);
    }
}

// ---------- fused conv2 + conv3-transform (MFMA; degree-sorted node blocks) ----------
__global__ void k_gconv2(const int* __restrict__ cursor, const int* __restrict__ csr,
                         const h8* __restrict__ tin, const float* __restrict__ dinv,
                         const float* __restrict__ W2, const float* __restrict__ b2,
                         const float* __restrict__ W3, const int* __restrict__ perm,
                         h8* __restrict__ tout, int N){
    __shared__ __align__(16) _Float16 sW[96*72];    // GEMM1: W2^T [96 col][72 k]; GEMM2: W3^T [48 col][104 k]
    __shared__ __align__(16) _Float16 sH2[48*104];  // H2 [48 row][104 k] (k 0..95 valid)
    __shared__ __align__(16) _Float16 sAgg[48*72];  // GEMM1 A [48 row][72 k]; reused as T3 [48 row][72]
    __shared__ float sb2[96];
    __shared__ float sDinv[48];
    __shared__ int   sPerm[48];
    int t  = threadIdx.x;
    int d0 = blockIdx.x*NPB;
    int nn = min(NPB, N - d0);

    // stage W2^T (zero-padded) + b2 + zero sAgg/sDinv (pads must be exactly 0)
    {
        int* z = (int*)sAgg;                       // 48*72 halves = 1728 dwords
        for(int i = t; i < 1728; i += 256) z[i] = 0;
        if(t < 96) sb2[t] = (t < 88) ? b2[t] : 0.f;
        if(t < 48) sDinv[t] = 0.f;
        for(int i = t; i < 96*72; i += 256){
            int c = i/72, k = i - c*72;
            sW[i] = (_Float16)((c < 88 && k < 44) ? W2[k*88 + c] : 0.f);
        }
    }
    __syncthreads();

    // phase 1: gather (6 threads per node, nodes = perm[d0..d0+nn)) -> sAgg f16
    int ln = t/6, c = t - ln*6;
    if(t < NPB*6 && ln < nn){
        int d = perm[d0 + ln];                     // similar-degree nodes per block
        float8 acc = gather_row(cursor, csr, tin, d, c);
        float dd = dinv[d];
        if(c == 0){ sDinv[ln] = dd; sPerm[ln] = d; }
        acc.lo.x *= dd; acc.lo.y *= dd; acc.lo.z *= dd; acc.lo.w *= dd;
        acc.hi.x *= dd; acc.hi.y *= dd; acc.hi.z *= dd; acc.hi.w *= dd;
        *(h8*)(sAgg + ln*72 + c*8) = f8toh8(acc);
    }
    __syncthreads();

    int w  = t >> 6;
    int l  = t & 63;
    int lr = l & 15;          // A-row / B-col / D-col within tile
    int lk = l >> 4;          // k-group (8 contiguous k per fragment)

    // phase 2 (GEMM1): H2 = relu(A @ W2 + b2); 18 tiles (3 mi x 6 ni), K=64 padded
    for(int tile = w; tile < 18; tile += 4){
        int mi = tile/6, ni = tile - mi*6;
        f16x8_t a0 = *(const f16x8_t*)(sAgg + (mi*16 + lr)*72 + lk*8);
        f16x8_t a1 = *(const f16x8_t*)(sAgg + (mi*16 + lr)*72 + 32 + lk*8);
        f16x8_t b0 = *(const f16x8_t*)(sW   + (ni*16 + lr)*72 + lk*8);
        f16x8_t b1 = *(const f16x8_t*)(sW   + (ni*16 + lr)*72 + 32 + lk*8);
        f32x4_t acc = {0.f, 0.f, 0.f, 0.f};
        acc = __builtin_amdgcn_mfma_f32_16x16x32_f16(a0, b0, acc, 0, 0, 0);
        acc = __builtin_amdgcn_mfma_f32_16x16x32_f16(a1, b1, acc, 0, 0, 0);
        int col = ni*16 + lr;
        float bb = sb2[col];
        int r0 = mi*16 + lk*4;
        #pragma unroll
        for(int r = 0; r < 4; r++)
            sH2[(r0 + r)*104 + col] = (_Float16)fmaxf(acc[r] + bb, 0.f);
    }
    __syncthreads();

    // restage W3^T [48 col][104 k] (zero-padded; pads MUST be 0: cols 44..47 are stored)
    for(int i = t; i < 48*104; i += 256){
        int cc_ = i/104, k = i - cc_*104;
        sW[i] = (_Float16)((cc_ < 44 && k < 88) ? W3[k*44 + cc_] : 0.f);
    }
    __syncthreads();

    // phase 3 (GEMM2): T3 = dinv .* (H2 @ W3); 9 tiles (3 mi x 3 ni), K=96 exact
    for(int tile = w; tile < 9; tile += 4){
        int mi = tile/3, ni = tile - mi*3;
        f32x4_t acc = {0.f, 0.f, 0.f, 0.f};
        #pragma unroll
        for(int ks = 0; ks < 3; ks++){
            f16x8_t a = *(const f16x8_t*)(sH2 + (mi*16 + lr)*104 + ks*32 + lk*8);
            f16x8_t b = *(const f16x8_t*)(sW  + (ni*16 + lr)*104 + ks*32 + lk*8);
            acc = __builtin_amdgcn_mfma_f32_16x16x32_f16(a, b, acc, 0, 0, 0);
        }
        int col = ni*16 + lr;
        int r0 = mi*16 + lk*4;
        #pragma unroll
        for(int r = 0; r < 4; r++)
            sAgg[(r0 + r)*72 + col] = (_Float16)(acc[r]*sDinv[r0 + r]);  // T3 into sAgg buffer
    }
    __syncthreads();

    // final: h8 stores of real rows (scattered by perm, bucket-local window)
    for(int o = t; o < nn*6; o += 256){
        int n_ = o/6, cc = o - n_*6;
        tout[(size_t)sPerm[n_]*6 + cc] = *(const h8*)(sAgg + n_*72 + cc*8);
    }
}

// tiny epilogue: 4 graphs/block (one wave each), reads pooled[G][48]
__global__ void k_headfin(const float* __restrict__ pooled, const float* __restrict__ partial,
                          const float* __restrict__ bf1, const float* __restrict__ Wf2,
                          const float* __restrict__ bf2, const float* __restrict__ Wg,
                          const float* __restrict__ bg, float* __restrict__ out,
                          int G, int H){
    int g    = blockIdx.x*4 + (threadIdx.x >> 6);
    int lane = threadIdx.x & 63;

    // x1 partial dot: lanes 0..43 each one feature
    float v = 0.f;
    if(lane < 44) v = pooled[(size_t)g*48 + lane]*Wg[lane];

    // x2: combine split-K partials
    float2 s = {0.f, 0.f};
    for(int ks = 0; ks < KS; ks++){
        float2 p = ((const float2*)(partial + ((size_t)ks*G + g)*H))[lane];
        s.x += p.x; s.y += p.y;
    }
    float2 b  = ((const float2*)bf1)[lane];
    float2 w2 = ((const float2*)Wf2)[lane];
    float y = fmaxf(s.x + b.x, 0.f)*w2.x + fmaxf(s.y + b.y, 0.f)*w2.y;

    for(int off = 32; off; off >>= 1){
        y += __shfl_xor(y, off, 64);
        v += __shfl_xor(v, off, 64);
    }
    if(lane == 0) out[g] = fmaxf(v + bg[0], 0.f) + y + bf2[0];
}

extern "C" void kernel_launch(void* const* d_in, const int* in_sizes, int n_in,
                              void* d_out, int out_size, void* d_ws, size_t ws_size,
                              hipStream_t stream) {
    const float* x       = (const float*)d_in[0];
    const int*   ei      = (const int*)  d_in[1];
    const int*   batch   = (const int*)  d_in[2];
    const float* feature = (const float*)d_in[3];
    const float* W1 = (const float*)d_in[4];  const float* b1 = (const float*)d_in[5];
    const float* W2 = (const float*)d_in[6];  const float* b2 = (const float*)d_in[7];
    const float* W3 = (const float*)d_in[8];  const float* b3 = (const float*)d_in[9];
    const float* Wg = (const float*)d_in[10]; const float* bg = (const float*)d_in[11];
    const float* Wf1= (const float*)d_in[12]; const float* bf1= (const float*)d_in[13];
    const float* Wf2= (const float*)d_in[14]; const float* bf2= (const float*)d_in[15];
    float* out = (float*)d_out;

    const int N    = in_sizes[2];          // 100000 (< 2^17 required by pair packing)
    const int E    = in_sizes[1] / 2;      // 1000000
    const int G    = out_size;             // 1024
    const int FEAT = in_sizes[3] / G;      // 1019
    const int H    = in_sizes[13];         // 128

    const int NB    = cdiv(N, 1 << BSH);   // 98 coarse buckets
    const int chunk = cdiv(E, NBLK1);
    const int NRG   = cdiv(N, 4);

    // workspace layout (4B units)
    float* wsf    = (float*)d_ws;
    float* dinv   = wsf;                          // N floats
    int*   cursor = (int*)(dinv + N);             // N ints
    int*   csr    = cursor + N;                   // E ints
    h8*    bufA   = (h8*)(csr + E);               // N*6 h8
    h8*    bufC   = bufA + (size_t)N*6;           // N*6 h8
    float* partial= (float*)(bufC + (size_t)N*6); // KS*G*H floats
    float* scratch= partial + (size_t)KS*G*H;
    int*   pairs  = (int*)scratch;                // E ints (packed; CSR build)
    int*   cnt_t  = pairs + E;                    // NBLK1*NB ints
    float* pooled = (float*)(cnt_t + NBLK1*NB);   // G*48 floats
    int*   perm   = (int*)(pooled + (size_t)G*48);// N ints (bucket-local degree sort)

    // ---- kernel 1: bucket count + head split-K GEMM (independent, merged) ----
    k_bcnt_head<<<NBLK1 + (G/GB)*KS, TPB, 0, stream>>>(
        ei + E, cnt_t, E, NB, chunk, feature, Wf1, partial, G, FEAT, H);

    // ---- CSR build (bscatter zeroes pooled; build emits bucket-local degree perm) ----
    k_bscatter<<<NBLK1, TPB, 0, stream>>>(ei, cnt_t, pairs, E, NB, chunk, pooled, G);
    k_build   <<<NB, TPB, 0, stream>>>(pairs, cnt_t, csr, cursor, dinv, perm, N, E, NB);

    // ---- conv1: bufA = dinv.*(x@W1) ; bufC = dinv.*relu(dinv*agg + b1) ----
    k_gemm1r <<<cdiv((long long)NRG*6, TPB), TPB, 0, stream>>>(x, W1, bufA, N, dinv);
    k_gather8<<<cdiv((long long)N*6, TPB), TPB, 0, stream>>>(cursor, csr, bufA, dinv, b1,
                                                             perm, bufC, N, 1);

    // ---- conv2 + conv3-transform fused (MFMA) ----
    k_gconv2 <<<cdiv(N, NPB), TPB, 0, stream>>>(cursor, csr, bufC, dinv, W2, b2, W3,
                                                perm, bufA, N);

    // ---- conv3 aggregate + pool fused (identity order: graph-local pooling) ----
    k_gather_pool<<<cdiv(N, NPP), TPB, 0, stream>>>(cursor, csr, bufA, dinv, b3, batch,
                                                    pooled, N);

    // ---- head epilogue ----
    k_headfin<<<G/4, 256, 0, stream>>>(pooled, partial, bf1, Wf2, bf2, Wg, bg, out, G, H);
}

// Round 10
// 284.489 us; speedup vs baseline: 1.1308x; 1.0473x over previous
//
#include <hip/hip_runtime.h>
#include <hip/hip_fp16.h>

#define TPB 256
#define NBLK1 256          // CSR pass-1 blocks
#define BSH 10             // bucket shift: 1024 nodes per bucket (NB <= 128)
#define MAXBE 12288        // max edges/bucket -> 48KB LDS
#define KS 8               // head GEMM K-splits
#define GB 8               // head GEMM graphs per block
#define NPB 42             // gconv2 nodes/block (42*6 = 252 <= 256)
#define NPP 42             // gather_pool nodes/block (252 tasks -> 1/thread)

static inline int cdiv(long long a, int b){ return (int)((a + b - 1)/b); }

typedef _Float16 f16x8_t __attribute__((ext_vector_type(8)));
typedef float    f32x4_t __attribute__((ext_vector_type(4)));

// 8 halves = 16 bytes, 16-byte aligned -> single dwordx4 loads
struct __align__(16) h8 { __half2 a, b, c, d; };
struct float8 { float4 lo, hi; };
__device__ inline float8 h8tof8(h8 v){
    float2 t0 = __half22float2(v.a), t1 = __half22float2(v.b);
    float2 t2 = __half22float2(v.c), t3 = __half22float2(v.d);
    float8 r;
    r.lo = make_float4(t0.x, t0.y, t1.x, t1.y);
    r.hi = make_float4(t2.x, t2.y, t3.x, t3.y);
    return r;
}
__device__ inline h8 f8toh8(float8 v){
    h8 r;
    r.a = __floats2half2_rn(v.lo.x, v.lo.y); r.b = __floats2half2_rn(v.lo.z, v.lo.w);
    r.c = __floats2half2_rn(v.hi.x, v.hi.y); r.d = __floats2half2_rn(v.hi.z, v.hi.w);
    return r;
}
__device__ inline void f8acc(float8& a, float8 v){
    a.lo.x += v.lo.x; a.lo.y += v.lo.y; a.lo.z += v.lo.z; a.lo.w += v.lo.w;
    a.hi.x += v.hi.x; a.hi.y += v.hi.y; a.hi.z += v.hi.z; a.hi.w += v.hi.w;
}
__device__ inline void f8fma(float8& a, float8 v, float m){
    a.lo.x = fmaf(v.lo.x, m, a.lo.x); a.lo.y = fmaf(v.lo.y, m, a.lo.y);
    a.lo.z = fmaf(v.lo.z, m, a.lo.z); a.lo.w = fmaf(v.lo.w, m, a.lo.w);
    a.hi.x = fmaf(v.hi.x, m, a.hi.x); a.hi.y = fmaf(v.hi.y, m, a.hi.y);
    a.hi.z = fmaf(v.hi.z, m, a.hi.z); a.hi.w = fmaf(v.hi.w, m, a.hi.w);
}

// ---------- kernel 1: bucket count (blocks 0..NBLK1) + head split-K GEMM (rest) ----------
__global__ void k_bcnt_head(const int* __restrict__ dst, int* __restrict__ cnt_t,
                            int E, int NB, int chunk,
                            const float* __restrict__ feature, const float* __restrict__ Wf1,
                            float* __restrict__ partial, int G, int FEAT, int H){
    __shared__ int hist[128];
    __shared__ float sfeat[128*GB];
    int t = threadIdx.x;
    if(blockIdx.x < NBLK1){
        // ---- bucket count ----
        int blk = blockIdx.x;
        for(int i = t; i < NB; i += blockDim.x) hist[i] = 0;
        __syncthreads();
        int lo = blk*chunk, hi = min(E, lo + chunk);
        for(int e = lo + t; e < hi; e += blockDim.x)
            atomicAdd(&hist[dst[e] >> BSH], 1);
        __syncthreads();
        for(int b = t; b < NB; b += blockDim.x)
            cnt_t[blk*NB + b] = hist[b];
    } else {
        // ---- head split-K GEMM: partial[ks][g][h] ----
        int bid = (int)blockIdx.x - NBLK1;          // 0..1023
        int g0 = (bid & 127)*GB;
        int ks = bid >> 7;
        int Kc = (FEAT + KS - 1)/KS;
        int k0 = ks*Kc;
        int k1 = min(FEAT, k0 + Kc);
        int kc = k1 - k0;
        for(int idx = t; idx < GB*128; idx += 256){
            int gi = idx >> 7, kk = idx & 127;
            if(kk < kc) sfeat[kk*GB + gi] = feature[(size_t)(g0+gi)*FEAT + k0 + kk];
        }
        __syncthreads();
        int h  = t & 127;
        int gq = t >> 7;
        const float* wp = Wf1 + (size_t)k0*H + h;
        float4 a = {0.f,0.f,0.f,0.f};
        const float4* sf = (const float4*)(sfeat) + gq;
        for(int kk = 0; kk < kc; kk++){
            float w = wp[(size_t)kk*H];
            float4 f = sf[kk*2];
            a.x += f.x*w; a.y += f.y*w; a.z += f.z*w; a.w += f.w*w;
        }
        float* pp = partial + ((size_t)ks*G + g0 + gq*4)*H + h;
        pp[0] = a.x; pp[H] = a.y; pp[2*H] = a.z; pp[3*H] = a.w;
    }
}

// scatter with inline prefix: pairs[pos] = (local_dst<<17)|src  (needs N < 2^17)
// also zeroes pooled[G*48] (65536 threads >= 49152 elems; stream-ordered before use)
__global__ void k_bscatter(const int* __restrict__ ei, const int* __restrict__ cnt_t,
                           int* __restrict__ pairs, int E, int NB, int chunk,
                           float* __restrict__ pooled, int G){
    __shared__ int cur[128];
    __shared__ int st[128];
    int blk = blockIdx.x;
    int t = threadIdx.x;
    int zi = blk*256 + t;
    if(zi < G*48) pooled[zi] = 0.f;
    int myp = 0, myt = 0;
    for(int b2 = 0; b2 < NBLK1; b2++){
        int v = (t < NB) ? cnt_t[b2*NB + t] : 0;
        myp += (b2 < blk) ? v : 0;
        myt += v;
    }
    if(t < NB){ cur[t] = myp; st[t] = myt; }
    __syncthreads();
    if(t == 0){
        int run = 0;
        for(int b = 0; b < NB; b++){ int v = st[b]; st[b] = run; run += v; }
    }
    __syncthreads();
    if(t < NB) cur[t] += st[t];
    __syncthreads();
    int lo = blk*chunk, hi = min(E, lo + chunk);
    for(int e = lo + t; e < hi; e += blockDim.x){
        int s = ei[e], d = ei[E + e];
        int pos = atomicAdd(&cur[d >> BSH], 1);          // LDS atomic
        pairs[pos] = ((d & ((1 << BSH) - 1)) << 17) | s; // packed
    }
}

__global__ void k_build(const int* __restrict__ pairs, const int* __restrict__ cnt_t,
                        int* __restrict__ csr, int* __restrict__ cursor,
                        float* __restrict__ dinv, int N, int E, int NB){
    __shared__ int stot[128];
    __shared__ int sBase, sCnt;
    __shared__ int c[1024];
    __shared__ int so[1024];
    __shared__ int part[256];
    __shared__ int csrl[MAXBE];
    int b = blockIdx.x;
    int t = threadIdx.x;
    int myt = 0;
    for(int b2 = 0; b2 < NBLK1; b2++)
        myt += (t < NB) ? cnt_t[b2*NB + t] : 0;
    if(t < NB) stot[t] = myt;
    __syncthreads();
    if(t == 0){
        int run = 0;
        for(int bb = 0; bb < NB; bb++){
            if(bb == b){ sBase = run; sCnt = stot[bb]; }
            run += stot[bb];
        }
    }
    __syncthreads();
    int base = sBase, cntE = sCnt;
    int n0 = b << BSH;
    int nn = min(1 << BSH, N - n0);

    for(int i = t; i < 1024; i += 256) c[i] = 0;
    __syncthreads();
    for(int i = t; i < cntE; i += 256)
        atomicAdd(&c[pairs[base + i] >> 17], 1);   // LDS atomic
    __syncthreads();
    int i0 = t*4;
    int l0 = c[i0], l1 = c[i0+1], l2 = c[i0+2], l3 = c[i0+3];
    part[t] = l0 + l1 + l2 + l3;
    __syncthreads();
    for(int off = 1; off < 256; off <<= 1){
        int u = (t >= off) ? part[t-off] : 0;
        __syncthreads();
        part[t] += u;
        __syncthreads();
    }
    int run = (t == 0) ? 0 : part[t-1];
    so[i0] = run; so[i0+1] = run + l0; so[i0+2] = run + l0 + l1; so[i0+3] = run + l0 + l1 + l2;
    __syncthreads();
    for(int i = t; i < nn; i += 256){
        int cc = c[i];
        cursor[n0 + i] = base + so[i] + cc;        // inclusive end offset
        dinv[n0 + i]   = rsqrtf((float)(cc + 1));  // +1 = self-loop
    }
    for(int i = t; i < 1024; i += 256) c[i] = so[i];
    __syncthreads();
    for(int i = t; i < cntE; i += 256){
        int v = pairs[base + i];
        int pos = atomicAdd(&c[v >> 17], 1);       // LDS atomic
        csrl[pos] = v & 0x1FFFF;
    }
    __syncthreads();
    for(int i = t; i < cntE; i += 256) csr[base + i] = csrl[i];   // coalesced
}

// ---------- gather core: self + neighbor sum of one 16B chunk ----------
// Best-measured structure (R4/R5 bench 285.5us): 8-wide main loop + single
// clamped masked 8-wide tail batch. Masks exact 0/1 -> bit-identical result.
__device__ inline float8 gather_row(const int* __restrict__ cursor,
                                    const int* __restrict__ csr,
                                    const h8* __restrict__ t, int d, int cg){
    int start = (d == 0) ? 0 : cursor[d-1];
    int end   = cursor[d];
    float8 a0 = h8tof8(t[(size_t)d*6 + cg]);     // self-loop
    float8 a1 = {{0,0,0,0},{0,0,0,0}}, a2 = a1, a3 = a1;
    int j = start;
    for(; j + 8 <= end; j += 8){
        int s0 = csr[j],   s1 = csr[j+1], s2 = csr[j+2], s3 = csr[j+3];
        int s4 = csr[j+4], s5 = csr[j+5], s6 = csr[j+6], s7 = csr[j+7];
        h8 r0 = t[(size_t)s0*6 + cg];            // 8 independent dwordx4 in flight
        h8 r1 = t[(size_t)s1*6 + cg];
        h8 r2 = t[(size_t)s2*6 + cg];
        h8 r3 = t[(size_t)s3*6 + cg];
        h8 r4 = t[(size_t)s4*6 + cg];
        h8 r5 = t[(size_t)s5*6 + cg];
        h8 r6 = t[(size_t)s6*6 + cg];
        h8 r7 = t[(size_t)s7*6 + cg];
        f8acc(a0, h8tof8(r0)); f8acc(a1, h8tof8(r1));
        f8acc(a2, h8tof8(r2)); f8acc(a3, h8tof8(r3));
        f8acc(a0, h8tof8(r4)); f8acc(a1, h8tof8(r5));
        f8acc(a2, h8tof8(r6)); f8acc(a3, h8tof8(r7));
    }
    int rem = end - j;
    if(rem > 0){
        int e1 = end - 1;
        int s0 = csr[j];
        int s1 = csr[min(j+1, e1)], s2 = csr[min(j+2, e1)], s3 = csr[min(j+3, e1)];
        int s4 = csr[min(j+4, e1)], s5 = csr[min(j+5, e1)], s6 = csr[min(j+6, e1)];
        int s7 = csr[min(j+7, e1)];
        h8 r0 = t[(size_t)s0*6 + cg];            // all tail loads in flight together
        h8 r1 = t[(size_t)s1*6 + cg];
        h8 r2 = t[(size_t)s2*6 + cg];
        h8 r3 = t[(size_t)s3*6 + cg];
        h8 r4 = t[(size_t)s4*6 + cg];
        h8 r5 = t[(size_t)s5*6 + cg];
        h8 r6 = t[(size_t)s6*6 + cg];
        h8 r7 = t[(size_t)s7*6 + cg];
        f8acc(a0, h8tof8(r0));                               // k=0 always valid
        f8fma(a1, h8tof8(r1), (1 < rem) ? 1.f : 0.f);
        f8fma(a2, h8tof8(r2), (2 < rem) ? 1.f : 0.f);
        f8fma(a3, h8tof8(r3), (3 < rem) ? 1.f : 0.f);
        f8fma(a0, h8tof8(r4), (4 < rem) ? 1.f : 0.f);
        f8fma(a1, h8tof8(r5), (5 < rem) ? 1.f : 0.f);
        f8fma(a2, h8tof8(r6), (6 < rem) ? 1.f : 0.f);
        f8fma(a3, h8tof8(r7), (7 < rem) ? 1.f : 0.f);
    }
    f8acc(a0, a1); f8acc(a2, a3); f8acc(a0, a2);
    return a0;
}

// ---------- conv1 GEMM, row-batched x4: t = dinv .* (x @ W1) ----------
__global__ void k_gemm1r(const float* __restrict__ x, const float* __restrict__ W,
                         h8* __restrict__ t, int n, const float* __restrict__ dinv){
    __shared__ float sW[44*48];                   // [k][48], zero-padded cols
    for(int i = threadIdx.x; i < 44*48; i += blockDim.x){
        int k = i/48, j = i - k*48;
        sW[i] = (j < 44) ? W[k*44 + j] : 0.f;
    }
    __syncthreads();
    int nrg = (n + 3) >> 2;
    unsigned total = (unsigned)nrg * 6u;
    unsigned idx = blockIdx.x*blockDim.x + threadIdx.x;
    if(idx >= total) return;
    unsigned rg = idx / 6u;
    unsigned cg = idx - rg*6u;
    int row0 = (int)rg*4;
    const float4* sWv = (const float4*)sW;        // 12 float4 per k
    float8 acc[4] = {{{0,0,0,0},{0,0,0,0}},{{0,0,0,0},{0,0,0,0}},
                     {{0,0,0,0},{0,0,0,0}},{{0,0,0,0},{0,0,0,0}}};
    for(int k4 = 0; k4 < 11; k4++){
        float fv[4][4];
        #pragma unroll
        for(int r = 0; r < 4; r++){
            int rr = min(row0 + r, n - 1);        // clamp (tail rows duplicate, store guarded)
            *(float4*)fv[r] = ((const float4*)(x + (size_t)rr*44))[k4];
        }
        int kb = k4*4;
        #pragma unroll
        for(int i = 0; i < 4; i++){
            float4 wlo = sWv[(unsigned)(kb+i)*12 + cg*2];
            float4 whi = sWv[(unsigned)(kb+i)*12 + cg*2 + 1];
            #pragma unroll
            for(int r = 0; r < 4; r++){
                float h = fv[r][i];
                acc[r].lo.x += h*wlo.x; acc[r].lo.y += h*wlo.y;
                acc[r].lo.z += h*wlo.z; acc[r].lo.w += h*wlo.w;
                acc[r].hi.x += h*whi.x; acc[r].hi.y += h*whi.y;
                acc[r].hi.z += h*whi.z; acc[r].hi.w += h*whi.w;
            }
        }
    }
    #pragma unroll
    for(int r = 0; r < 4; r++){
        int row = row0 + r;
        if(row < n){
            float dd = dinv[row];
            acc[r].lo.x *= dd; acc[r].lo.y *= dd; acc[r].lo.z *= dd; acc[r].lo.w *= dd;
            acc[r].hi.x *= dd; acc[r].hi.y *= dd; acc[r].hi.z *= dd; acc[r].hi.w *= dd;
            t[(size_t)row*6 + cg] = f8toh8(acc[r]);
        }
    }
}

// ---------- plain gather: out = [prescale][relu-if-bias](dinv*agg [+ bias]) ----------
__global__ void k_gather8(const int* __restrict__ cursor, const int* __restrict__ csr,
                          const h8* __restrict__ t, const float* __restrict__ dinv,
                          const float* __restrict__ bias, h8* __restrict__ out,
                          int n, int prescale_out){
    __shared__ float sb[48];
    if(threadIdx.x < 48) sb[threadIdx.x] = (bias && threadIdx.x < 44) ? bias[threadIdx.x] : 0.f;
    __syncthreads();
    unsigned total  = (unsigned)n * 6u;
    unsigned stride = gridDim.x * blockDim.x;
    const float4* sb4 = (const float4*)sb;
    for(unsigned idx = blockIdx.x*blockDim.x + threadIdx.x; idx < total; idx += stride){
        unsigned d  = idx / 6u;
        unsigned cg = idx - d*6u;
        float8 acc = gather_row(cursor, csr, t, (int)d, (int)cg);
        float dd = dinv[d];
        float4 blo = sb4[cg*2], bhi = sb4[cg*2+1];
        acc.lo.x = acc.lo.x*dd + blo.x; acc.lo.y = acc.lo.y*dd + blo.y;
        acc.lo.z = acc.lo.z*dd + blo.z; acc.lo.w = acc.lo.w*dd + blo.w;
        acc.hi.x = acc.hi.x*dd + bhi.x; acc.hi.y = acc.hi.y*dd + bhi.y;
        acc.hi.z = acc.hi.z*dd + bhi.z; acc.hi.w = acc.hi.w*dd + bhi.w;
        if(bias){
            acc.lo.x = fmaxf(acc.lo.x, 0.f); acc.lo.y = fmaxf(acc.lo.y, 0.f);
            acc.lo.z = fmaxf(acc.lo.z, 0.f); acc.lo.w = fmaxf(acc.lo.w, 0.f);
            acc.hi.x = fmaxf(acc.hi.x, 0.f); acc.hi.y = fmaxf(acc.hi.y, 0.f);
            acc.hi.z = fmaxf(acc.hi.z, 0.f); acc.hi.w = fmaxf(acc.hi.w, 0.f);
        }
        if(prescale_out){
            acc.lo.x *= dd; acc.lo.y *= dd; acc.lo.z *= dd; acc.lo.w *= dd;
            acc.hi.x *= dd; acc.hi.y *= dd; acc.hi.z *= dd; acc.hi.w *= dd;
        }
        out[(size_t)d*6 + cg] = f8toh8(acc);
    }
}

// ---------- fused conv3-aggregate + global max pool ----------
// relu(dinv*agg(bufA) + b3) per node in fp32, max-reduced into pooled[G][48]
// (LDS atomicMax + one global atomicMax per (graph,feature) per block).
__global__ void k_gather_pool(const int* __restrict__ cursor, const int* __restrict__ csr,
                              const h8* __restrict__ t, const float* __restrict__ dinv,
                              const float* __restrict__ bias, const int* __restrict__ batch,
                              float* __restrict__ pooled, int n){
    __shared__ float sb[48];
    __shared__ unsigned spool[3*48];             // NPP=42 nodes span <=2 graphs; 3 for safety
    int tid = threadIdx.x;
    if(tid < 48) sb[tid] = (tid < 44) ? bias[tid] : 0.f;
    for(int i = tid; i < 3*48; i += 256) spool[i] = 0u;
    int d0 = blockIdx.x*NPP;
    __syncthreads();
    int g0 = batch[d0];
    int tasks = min(NPP, n - d0)*6;
    const float4* sb4 = (const float4*)sb;
    for(int o = tid; o < tasks; o += 256){
        int ln = o/6, cg = o - ln*6;
        int d = d0 + ln;
        float8 acc = gather_row(cursor, csr, t, d, cg);
        float dd = dinv[d];
        float4 blo = sb4[cg*2], bhi = sb4[cg*2+1];
        acc.lo.x = fmaxf(acc.lo.x*dd + blo.x, 0.f); acc.lo.y = fmaxf(acc.lo.y*dd + blo.y, 0.f);
        acc.lo.z = fmaxf(acc.lo.z*dd + blo.z, 0.f); acc.lo.w = fmaxf(acc.lo.w*dd + blo.w, 0.f);
        acc.hi.x = fmaxf(acc.hi.x*dd + bhi.x, 0.f); acc.hi.y = fmaxf(acc.hi.y*dd + bhi.y, 0.f);
        acc.hi.z = fmaxf(acc.hi.z*dd + bhi.z, 0.f); acc.hi.w = fmaxf(acc.hi.w*dd + bhi.w, 0.f);
        int gi = batch[d] - g0;                  // 0..2
        unsigned* sp = spool + gi*48 + cg*8;
        atomicMax(&sp[0], __float_as_uint(acc.lo.x));
        atomicMax(&sp[1], __float_as_uint(acc.lo.y));
        atomicMax(&sp[2], __float_as_uint(acc.lo.z));
        atomicMax(&sp[3], __float_as_uint(acc.lo.w));
        atomicMax(&sp[4], __float_as_uint(acc.hi.x));
        atomicMax(&sp[5], __float_as_uint(acc.hi.y));
        atomicMax(&sp[6], __float_as_uint(acc.hi.z));
        atomicMax(&sp[7], __float_as_uint(acc.hi.w));
    }
    __syncthreads();
    for(int i = tid; i < 3*48; i += 256){
        unsigned v = spool[i];
        if(v) atomicMax((unsigned*)&pooled[(size_t)(g0 + i/48)*48 + (i - (i/48)*48)], v);
    }
}

// ---------- fused conv2 + conv3-transform (MFMA, 256 threads — R2-verified) ----------
__global__ void k_gconv2(const int* __restrict__ cursor, const int* __restrict__ csr,
                         const h8* __restrict__ tin, const float* __restrict__ dinv,
                         const float* __restrict__ W2, const float* __restrict__ b2,
                         const float* __restrict__ W3, h8* __restrict__ tout, int N){
    __shared__ __align__(16) _Float16 sW[96*72];    // GEMM1: W2^T [96 col][72 k]; GEMM2: W3^T [48 col][104 k]
    __shared__ __align__(16) _Float16 sH2[48*104];  // H2 [48 row][104 k] (k 0..95 valid)
    __shared__ __align__(16) _Float16 sAgg[48*72];  // GEMM1 A [48 row][72 k]; reused as T3 [48 row][72]
    __shared__ float sb2[96];
    __shared__ float sDinv[48];
    int t  = threadIdx.x;
    int d0 = blockIdx.x*NPB;
    int nn = min(NPB, N - d0);

    // stage W2^T (zero-padded) + b2 + zero sAgg/sDinv (pads must be exactly 0)
    {
        int* z = (int*)sAgg;                       // 48*72 halves = 1728 dwords
        for(int i = t; i < 1728; i += 256) z[i] = 0;
        if(t < 96) sb2[t] = (t < 88) ? b2[t] : 0.f;
        if(t < 48) sDinv[t] = 0.f;
        for(int i = t; i < 96*72; i += 256){
            int c = i/72, k = i - c*72;
            sW[i] = (_Float16)((c < 88 && k < 44) ? W2[k*88 + c] : 0.f);
        }
    }
    __syncthreads();

    // phase 1: gather (6 threads per node) -> sAgg f16 [row][72]
    int ln = t/6, c = t - ln*6;
    if(t < NPB*6 && ln < nn){
        int d = d0 + ln;
        float8 acc = gather_row(cursor, csr, tin, d, c);
        float dd = dinv[d];
        if(c == 0) sDinv[ln] = dd;
        acc.lo.x *= dd; acc.lo.y *= dd; acc.lo.z *= dd; acc.lo.w *= dd;
        acc.hi.x *= dd; acc.hi.y *= dd; acc.hi.z *= dd; acc.hi.w *= dd;
        *(h8*)(sAgg + ln*72 + c*8) = f8toh8(acc);
    }
    __syncthreads();

    int w  = t >> 6;
    int l  = t & 63;
    int lr = l & 15;          // A-row / B-col / D-col within tile
    int lk = l >> 4;          // k-group (8 contiguous k per fragment)

    // phase 2 (GEMM1): H2 = relu(A @ W2 + b2); 18 tiles (3 mi x 6 ni), K=64 padded
    for(int tile = w; tile < 18; tile += 4){
        int mi = tile/6, ni = tile - mi*6;
        f16x8_t a0 = *(const f16x8_t*)(sAgg + (mi*16 + lr)*72 + lk*8);
        f16x8_t a1 = *(const f16x8_t*)(sAgg + (mi*16 + lr)*72 + 32 + lk*8);
        f16x8_t b0 = *(const f16x8_t*)(sW   + (ni*16 + lr)*72 + lk*8);
        f16x8_t b1 = *(const f16x8_t*)(sW   + (ni*16 + lr)*72 + 32 + lk*8);
        f32x4_t acc = {0.f, 0.f, 0.f, 0.f};
        acc = __builtin_amdgcn_mfma_f32_16x16x32_f16(a0, b0, acc, 0, 0, 0);
        acc = __builtin_amdgcn_mfma_f32_16x16x32_f16(a1, b1, acc, 0, 0, 0);
        int col = ni*16 + lr;
        float bb = sb2[col];
        int r0 = mi*16 + lk*4;
        #pragma unroll
        for(int r = 0; r < 4; r++)
            sH2[(r0 + r)*104 + col] = (_Float16)fmaxf(acc[r] + bb, 0.f);
    }
    __syncthreads();

    // restage W3^T [48 col][104 k] (zero-padded; pads MUST be 0: cols 44..47 are stored)
    for(int i = t; i < 48*104; i += 256){
        int cc_ = i/104, k = i - cc_*104;
        sW[i] = (_Float16)((cc_ < 44 && k < 88) ? W3[k*44 + cc_] : 0.f);
    }
    __syncthreads();

    // phase 3 (GEMM2): T3 = dinv .* (H2 @ W3); 9 tiles (3 mi x 3 ni), K=96 exact
    for(int tile = w; tile < 9; tile += 4){
        int mi = tile/3, ni = tile - mi*3;
        f32x4_t acc = {0.f, 0.f, 0.f, 0.f};
        #pragma unroll
        for(int ks = 0; ks < 3; ks++){
            f16x8_t a = *(const f16x8_t*)(sH2 + (mi*16 + lr)*104 + ks*32 + lk*8);
            f16x8_t b = *(const f16x8_t*)(sW  + (ni*16 + lr)*104 + ks*32 + lk*8);
            acc = __builtin_amdgcn_mfma_f32_16x16x32_f16(a, b, acc, 0, 0, 0);
        }
        int col = ni*16 + lr;
        int r0 = mi*16 + lk*4;
        #pragma unroll
        for(int r = 0; r < 4; r++)
            sAgg[(r0 + r)*72 + col] = (_Float16)(acc[r]*sDinv[r0 + r]);  // T3 into sAgg buffer
    }
    __syncthreads();

    // final: coalesced h8 stores of real rows
    for(int o = t; o < nn*6; o += 256){
        int n_ = o/6, cc = o - n_*6;
        tout[(size_t)(d0 + n_)*6 + cc] = *(const h8*)(sAgg + n_*72 + cc*8);
    }
}

// tiny epilogue: 4 graphs/block (one wave each), reads pooled[G][48]
__global__ void k_headfin(const float* __restrict__ pooled, const float* __restrict__ partial,
                          const float* __restrict__ bf1, const float* __restrict__ Wf2,
                          const float* __restrict__ bf2, const float* __restrict__ Wg,
                          const float* __restrict__ bg, float* __restrict__ out,
                          int G, int H){
    int g    = blockIdx.x*4 + (threadIdx.x >> 6);
    int lane = threadIdx.x & 63;

    // x1 partial dot: lanes 0..43 each one feature
    float v = 0.f;
    if(lane < 44) v = pooled[(size_t)g*48 + lane]*Wg[lane];

    // x2: combine split-K partials
    float2 s = {0.f, 0.f};
    for(int ks = 0; ks < KS; ks++){
        float2 p = ((const float2*)(partial + ((size_t)ks*G + g)*H))[lane];
        s.x += p.x; s.y += p.y;
    }
    float2 b  = ((const float2*)bf1)[lane];
    float2 w2 = ((const float2*)Wf2)[lane];
    float y = fmaxf(s.x + b.x, 0.f)*w2.x + fmaxf(s.y + b.y, 0.f)*w2.y;

    for(int off = 32; off; off >>= 1){
        y += __shfl_xor(y, off, 64);
        v += __shfl_xor(v, off, 64);
    }
    if(lane == 0) out[g] = fmaxf(v + bg[0], 0.f) + y + bf2[0];
}

extern "C" void kernel_launch(void* const* d_in, const int* in_sizes, int n_in,
                              void* d_out, int out_size, void* d_ws, size_t ws_size,
                              hipStream_t stream) {
    const float* x       = (const float*)d_in[0];
    const int*   ei      = (const int*)  d_in[1];
    const int*   batch   = (const int*)  d_in[2];
    const float* feature = (const float*)d_in[3];
    const float* W1 = (const float*)d_in[4];  const float* b1 = (const float*)d_in[5];
    const float* W2 = (const float*)d_in[6];  const float* b2 = (const float*)d_in[7];
    const float* W3 = (const float*)d_in[8];  const float* b3 = (const float*)d_in[9];
    const float* Wg = (const float*)d_in[10]; const float* bg = (const float*)d_in[11];
    const float* Wf1= (const float*)d_in[12]; const float* bf1= (const float*)d_in[13];
    const float* Wf2= (const float*)d_in[14]; const float* bf2= (const float*)d_in[15];
    float* out = (float*)d_out;

    const int N    = in_sizes[2];          // 100000 (< 2^17 required by pair packing)
    const int E    = in_sizes[1] / 2;      // 1000000
    const int G    = out_size;             // 1024
    const int FEAT = in_sizes[3] / G;      // 1019
    const int H    = in_sizes[13];         // 128

    const int NB    = cdiv(N, 1 << BSH);   // 98 coarse buckets
    const int chunk = cdiv(E, NBLK1);
    const int NRG   = cdiv(N, 4);

    // workspace layout (4B units)
    float* wsf    = (float*)d_ws;
    float* dinv   = wsf;                          // N floats
    int*   cursor = (int*)(dinv + N);             // N ints
    int*   csr    = cursor + N;                   // E ints
    h8*    bufA   = (h8*)(csr + E);               // N*6 h8
    h8*    bufC   = bufA + (size_t)N*6;           // N*6 h8
    float* partial= (float*)(bufC + (size_t)N*6); // KS*G*H floats
    float* scratch= partial + (size_t)KS*G*H;
    int*   pairs  = (int*)scratch;                // E ints (packed; CSR build)
    int*   cnt_t  = pairs + E;                    // NBLK1*NB ints
    float* pooled = (float*)(cnt_t + NBLK1*NB);   // G*48 floats

    // ---- kernel 1: bucket count + head split-K GEMM (independent, merged) ----
    k_bcnt_head<<<NBLK1 + (G/GB)*KS, TPB, 0, stream>>>(
        ei + E, cnt_t, E, NB, chunk, feature, Wf1, partial, G, FEAT, H);

    // ---- CSR build (bscatter also zeroes pooled) ----
    k_bscatter<<<NBLK1, TPB, 0, stream>>>(ei, cnt_t, pairs, E, NB, chunk, pooled, G);
    k_build   <<<NB, TPB, 0, stream>>>(pairs, cnt_t, csr, cursor, dinv, N, E, NB);

    // ---- conv1: bufA = dinv.*(x@W1) ; bufC = dinv.*relu(dinv*agg + b1) ----
    k_gemm1r <<<cdiv((long long)NRG*6, TPB), TPB, 0, stream>>>(x, W1, bufA, N, dinv);
    k_gather8<<<cdiv((long long)N*6, TPB), TPB, 0, stream>>>(cursor, csr, bufA, dinv, b1, bufC, N, 1);

    // ---- conv2 + conv3-transform fused (MFMA, 256 threads) ----
    k_gconv2 <<<cdiv(N, NPB), TPB, 0, stream>>>(cursor, csr, bufC, dinv, W2, b2, W3, bufA, N);

    // ---- conv3 aggregate + pool fused ----
    k_gather_pool<<<cdiv(N, NPP), TPB, 0, stream>>>(cursor, csr, bufA, dinv, b3, batch,
                                                    pooled, N);

    // ---- head epilogue ----
    k_headfin<<<G/4, 256, 0, stream>>>(pooled, partial, bf1, Wf2, bf2, Wg, bg, out, G, H);
}